// Round 15
// baseline (146.642 us; speedup 1.0000x reference)
//
#include <hip/hip_runtime.h>
#include <math.h>

#define NPTS 65536

__device__ __forceinline__ float4 ld4_guard(const float* __restrict__ row, int pos, int hi) {
    float4 v;
    if (pos >= 0 && pos + 4 <= hi) {
        v = *(const float4*)(row + pos);
    } else {
        v.x = (pos + 0 >= 0 && pos + 0 < hi) ? row[pos + 0] : 0.f;
        v.y = (pos + 1 >= 0 && pos + 1 < hi) ? row[pos + 1] : 0.f;
        v.z = (pos + 2 >= 0 && pos + 2 < hi) ? row[pos + 2] : 0.f;
        v.w = (pos + 3 >= 0 && pos + 3 < hi) ? row[pos + 3] : 0.f;
    }
    return v;
}

// pad 4 floats every 32: breaks 128B-stride aliasing, float4-safe.
__device__ __forceinline__ int pmap(int p) { return p + ((p >> 5) << 2); }

// =====================================================================
// transpose x (B,N,2) -> x_t (N, 64)
// =====================================================================
__global__ __launch_bounds__(256) void transpose_kernel(const float* __restrict__ x,
                                                        float* __restrict__ xt)
{
    __shared__ float tile[64][65];
    int n0 = blockIdx.x * 64;
    int tid = threadIdx.x;
    int lane = tid & 63, w = tid >> 6;
    const float2* x2 = (const float2*)x;
#pragma unroll
    for (int bq = 0; bq < 8; ++bq) {
        int b = bq * 4 + w;
        float2 v = x2[(size_t)b * NPTS + n0 + lane];
        tile[lane][b * 2 + 0] = v.x;
        tile[lane][b * 2 + 1] = v.y;
    }
    __syncthreads();
    int f4 = tid & 15;
#pragma unroll
    for (int rq = 0; rq < 4; ++rq) {
        int r = rq * 16 + (tid >> 4);
        float4 v = make_float4(tile[r][f4 * 4 + 0], tile[r][f4 * 4 + 1],
                               tile[r][f4 * 4 + 2], tile[r][f4 * 4 + 3]);
        *(float4*)&xt[(size_t)(n0 + r) * 64 + f4 * 4] = v;
    }
}

// =====================================================================
// smooth, both SFC in one launch: i = bid>>9, tile t = bid&511.
// s_out layout: s0 + i*4194304 + (b*2+c)*N + n.
// =====================================================================
__global__ __launch_bounds__(256) void smooth2_kernel(const float* __restrict__ xt,
                                                      const int* __restrict__ ord0,
                                                      const float* __restrict__ sp_w,
                                                      const float* __restrict__ sp_b,
                                                      float* __restrict__ s0)
{
    __shared__ int s_idx[130];
    __shared__ float rows[130][65];
    int bid = blockIdx.x;
    int i = bid >> 9;
    int t = bid & 511;
    const int* ord = ord0 + (size_t)i * NPTS;
    float* s = s0 + (size_t)i * 4194304;
    int n0 = t * 128;
    int tid = threadIdx.x;
    if (tid < 130) {
        int g = n0 - 1 + tid;
        g = g < 0 ? 0 : (g > NPTS - 1 ? NPTS - 1 : g);
        s_idx[tid] = ord[g];
    }
    __syncthreads();
    for (int q = tid; q < 130 * 16; q += 256) {
        int r = q >> 4, f4 = q & 15;
        float4 v = *(const float4*)&xt[(size_t)s_idx[r] * 64 + f4 * 4];
        rows[r][f4 * 4 + 0] = v.x; rows[r][f4 * 4 + 1] = v.y;
        rows[r][f4 * 4 + 2] = v.z; rows[r][f4 * 4 + 3] = v.w;
    }
    __syncthreads();
    int n_local = tid & 127, half = tid >> 7;
    int n = n0 + n_local;
    float w0 = sp_w[n * 3 + 0], w1 = sp_w[n * 3 + 1], w2 = sp_w[n * 3 + 2];
    float bb = sp_b[n];
#pragma unroll 4
    for (int bc = 0; bc < 64; bc += 2) {
        int bce = bc + half;
        float v = w0 * rows[n_local][bce] + w1 * rows[n_local + 1][bce]
                + w2 * rows[n_local + 2][bce] + bb;
        s[(size_t)bce * NPTS + n] = tanhf(v);
    }
}

// =====================================================================
// conv0 wave-per-co: 4 waves = 4 co; lane owns 8 consecutive l.
// =====================================================================
__global__ __launch_bounds__(256, 2) void conv0_wpc(
    const float* __restrict__ in,      // s: rows (b*2+ci)*NPTS
    const float* __restrict__ w,       // (4,2,32)
    const float* __restrict__ bias,
    float* __restrict__ out)           // (B,4,16388), valid l<16385
{
    constexpr int SPAN = 2076;
    __shared__ float in_s[2][2336];

    int bid = blockIdx.x;
    int tile = bid % 33;
    int b = bid / 33;
    int tid = threadIdx.x;

    int base = tile * 2048 - 16;
    const float* inb = in + (size_t)b * 2 * NPTS;
    for (int q = tid; q < 2 * (SPAN / 4); q += 256) {
        int ci = q / (SPAN / 4), fp = q - ci * (SPAN / 4);
        int p = 4 * fp;
        float4 v = ld4_guard(inb + (size_t)ci * NPTS, base + p, NPTS);
        *(float4*)&in_s[ci][pmap(p)] = v;
    }
    __syncthreads();

    int lane = tid & 63;
    int co_u = __builtin_amdgcn_readfirstlane(tid >> 6);

    float acc[8];
    float bv = bias[co_u];
#pragma unroll
    for (int j = 0; j < 8; ++j) acc[j] = bv;

#pragma unroll 1
    for (int ci = 0; ci < 2; ++ci) {
        const float* wb = w + (co_u * 2 + ci) * 32;
        float wv[32];
#pragma unroll
        for (int k = 0; k < 32; ++k) wv[k] = wb[k];
        float4 v[15];
#pragma unroll
        for (int k = 0; k < 15; ++k)
            v[k] = *(const float4*)&in_s[ci][pmap(32 * lane + 4 * k)];
#pragma unroll
        for (int k4 = 0; k4 < 8; ++k4) {
            float wx = wv[4 * k4], wy = wv[4 * k4 + 1], wz = wv[4 * k4 + 2], ww = wv[4 * k4 + 3];
#pragma unroll
            for (int j = 0; j < 8; ++j)
                acc[j] += v[j + k4].x * wx + v[j + k4].y * wy
                        + v[j + k4].z * wz + v[j + k4].w * ww;
        }
    }

    int l0 = tile * 512 + lane * 8;
    size_t row = ((size_t)b * 4 + co_u) * 16388;
    if (l0 + 8 <= 16385) {
        float4 s0 = make_float4(tanhf(acc[0]), tanhf(acc[1]), tanhf(acc[2]), tanhf(acc[3]));
        float4 s1 = make_float4(tanhf(acc[4]), tanhf(acc[5]), tanhf(acc[6]), tanhf(acc[7]));
        *(float4*)&out[row + l0] = s0;
        *(float4*)&out[row + l0 + 4] = s1;
    } else {
#pragma unroll
        for (int j = 0; j < 8; ++j)
            if (l0 + j < 16385) out[row + l0 + j] = tanhf(acc[j]);
    }
}

// =====================================================================
// conv1, 256 threads: 4 waves own co pairs {w, w+4}; lane owns 4 l.
// LDS 18.9 KB -> 8 blocks/CU.
// =====================================================================
__global__ __launch_bounds__(256, 2) void conv1_wpc(
    const float* __restrict__ in,      // c0 (B,4,16388), valid 16385
    const float* __restrict__ w,       // (8,4,32)
    const float* __restrict__ bias,
    float* __restrict__ out)           // (B,8,4100), valid l<4097
{
    constexpr int SPAN = 1052;
    __shared__ float in_s[4][1184];

    int bid = blockIdx.x;
    int tile = bid % 17;
    int b = bid / 17;
    int tid = threadIdx.x;

    int base = tile * 1024 - 16;
    const float* inb = in + (size_t)b * 4 * 16388;
    for (int q = tid; q < 4 * (SPAN / 4); q += 256) {
        int ci = q / (SPAN / 4), fp = q - ci * (SPAN / 4);
        int p = 4 * fp;
        float4 v = ld4_guard(inb + (size_t)ci * 16388, base + p, 16385);
        *(float4*)&in_s[ci][pmap(p)] = v;
    }
    __syncthreads();

    int lane = tid & 63;
    int co_u = __builtin_amdgcn_readfirstlane(tid >> 6);   // 0..3

    float acc[2][4];
    float b0 = bias[co_u], b1v = bias[co_u + 4];
#pragma unroll
    for (int j = 0; j < 4; ++j) { acc[0][j] = b0; acc[1][j] = b1v; }

#pragma unroll 1
    for (int ci = 0; ci < 4; ++ci) {
        const float* wa = w + (size_t)(co_u * 4 + ci) * 32;
        const float* wb = w + (size_t)((co_u + 4) * 4 + ci) * 32;
        float4 v[11];
#pragma unroll
        for (int k = 0; k < 11; ++k)
            v[k] = *(const float4*)&in_s[ci][pmap(16 * lane + 4 * k)];
#pragma unroll
        for (int k4 = 0; k4 < 8; ++k4) {
            float4 wva = *(const float4*)(wa + 4 * k4);
            float4 wvb = *(const float4*)(wb + 4 * k4);
#pragma unroll
            for (int j = 0; j < 4; ++j) {
                acc[0][j] += v[k4 + j].x * wva.x + v[k4 + j].y * wva.y
                           + v[k4 + j].z * wva.z + v[k4 + j].w * wva.w;
                acc[1][j] += v[k4 + j].x * wvb.x + v[k4 + j].y * wvb.y
                           + v[k4 + j].z * wvb.z + v[k4 + j].w * wvb.w;
            }
        }
    }

    int l0 = tile * 256 + lane * 4;
#pragma unroll
    for (int h = 0; h < 2; ++h) {
        size_t row = ((size_t)b * 8 + co_u + 4 * h) * 4100;
        if (l0 + 4 <= 4097) {
            float4 s0 = make_float4(tanhf(acc[h][0]), tanhf(acc[h][1]),
                                    tanhf(acc[h][2]), tanhf(acc[h][3]));
            *(float4*)&out[row + l0] = s0;
        } else {
#pragma unroll
            for (int j = 0; j < 4; ++j)
                if (l0 + j < 4097) out[row + l0 + j] = tanhf(acc[h][j]);
        }
    }
}

// =====================================================================
// conv2, 256 threads: 4 waves own co {w, w+4, w+8, w+12}; lane owns 2 l.
// Tile 128 outputs, LDS 19.5 KB -> 8 blocks/CU, grid B*9.
// =====================================================================
__global__ __launch_bounds__(256, 2) void conv2_wpc(
    const float* __restrict__ in,      // c1 (B,8,4100), valid 4097
    const float* __restrict__ w,       // (16,8,32)
    const float* __restrict__ bias,
    float* __restrict__ out)           // (B,16,1028), valid l<1025
{
    constexpr int SPAN = 540;
    __shared__ float in_s[8][608];

    int bid = blockIdx.x;
    int tile = bid % 9;
    int b = bid / 9;
    int tid = threadIdx.x;

    int base = tile * 512 - 16;
    const float* inb = in + (size_t)b * 8 * 4100;
    for (int q = tid; q < 8 * (SPAN / 4); q += 256) {
        int ci = q / (SPAN / 4), fp = q - ci * (SPAN / 4);
        int p = 4 * fp;
        float4 v = ld4_guard(inb + (size_t)ci * 4100, base + p, 4097);
        *(float4*)&in_s[ci][pmap(p)] = v;
    }
    __syncthreads();

    int lane = tid & 63;
    int co_u = __builtin_amdgcn_readfirstlane(tid >> 6);   // 0..3

    float acc[4][2];
#pragma unroll
    for (int c = 0; c < 4; ++c) {
        float bv = bias[co_u + 4 * c];
        acc[c][0] = bv; acc[c][1] = bv;
    }

#pragma unroll 1
    for (int ci = 0; ci < 8; ++ci) {
        float4 v[9];
#pragma unroll
        for (int k = 0; k < 9; ++k)
            v[k] = *(const float4*)&in_s[ci][pmap(8 * lane + 4 * k)];
#pragma unroll
        for (int k4 = 0; k4 < 8; ++k4) {
#pragma unroll
            for (int c = 0; c < 4; ++c) {
                float4 wv = *(const float4*)(w + (size_t)((co_u + 4 * c) * 8 + ci) * 32 + 4 * k4);
#pragma unroll
                for (int j = 0; j < 2; ++j)
                    acc[c][j] += v[k4 + j].x * wv.x + v[k4 + j].y * wv.y
                               + v[k4 + j].z * wv.z + v[k4 + j].w * wv.w;
            }
        }
    }

    int l0 = tile * 128 + lane * 2;
#pragma unroll
    for (int c = 0; c < 4; ++c) {
        size_t row = ((size_t)b * 16 + co_u + 4 * c) * 1028;
        if (l0 + 2 <= 1025) {
            float2 st2 = make_float2(tanhf(acc[c][0]), tanhf(acc[c][1]));
            *(float2*)&out[row + l0] = st2;
        } else {
#pragma unroll
            for (int j = 0; j < 2; ++j)
                if (l0 + j < 1025) out[row + l0 + j] = tanhf(acc[c][j]);
        }
    }
}

// =====================================================================
// conv3, 256 threads: 4 waves own co {w, w+4, w+8, w+12}; lane owns 1 l.
// Tile 64 outputs, LDS 20.5 KB -> 7 blocks/CU, grid B*5.
// =====================================================================
__global__ __launch_bounds__(256, 2) void conv3_wpc(
    const float* __restrict__ in,      // c2 (B,16,1028), valid 1025
    const float* __restrict__ w,       // (16,16,32)
    const float* __restrict__ bias,
    float* __restrict__ out)           // (B,16,260), valid l<257
{
    constexpr int SPAN = 284;
    __shared__ float in_s[16][320];

    int bid = blockIdx.x;
    int tile = bid % 5;
    int b = bid / 5;
    int tid = threadIdx.x;

    int base = tile * 256 - 16;
    const float* inb = in + (size_t)b * 16 * 1028;
    for (int q = tid; q < 16 * (SPAN / 4); q += 256) {
        int ci = q / (SPAN / 4), fp = q - ci * (SPAN / 4);
        int p = 4 * fp;
        float4 v = ld4_guard(inb + (size_t)ci * 1028, base + p, 1025);
        *(float4*)&in_s[ci][pmap(p)] = v;
    }
    __syncthreads();

    int lane = tid & 63;
    int co_u = __builtin_amdgcn_readfirstlane(tid >> 6);   // 0..3

    float acc[4];
#pragma unroll
    for (int c = 0; c < 4; ++c) acc[c] = bias[co_u + 4 * c];

#pragma unroll 1
    for (int ci = 0; ci < 16; ++ci) {
        float4 v[8];
#pragma unroll
        for (int k = 0; k < 8; ++k)
            v[k] = *(const float4*)&in_s[ci][pmap(4 * lane + 4 * k)];
#pragma unroll
        for (int k4 = 0; k4 < 8; ++k4) {
#pragma unroll
            for (int c = 0; c < 4; ++c) {
                float4 wv = *(const float4*)(w + (size_t)((co_u + 4 * c) * 16 + ci) * 32 + 4 * k4);
                acc[c] += v[k4].x * wv.x + v[k4].y * wv.y
                        + v[k4].z * wv.z + v[k4].w * wv.w;
            }
        }
    }

    int l3 = tile * 64 + lane;
    if (l3 < 257) {
#pragma unroll
        for (int c = 0; c < 4; ++c)
            out[((size_t)b * 16 + co_u + 4 * c) * 260 + l3] = tanhf(acc[c]);
    }
}

// =====================================================================
// conv4 + concat into feats. Block = (b, co-half), pmap-padded st.
// =====================================================================
__global__ __launch_bounds__(256) void conv4_kernel(
    const float* __restrict__ c3,      // (B, 16, 260), valid l3 < 257
    const float* __restrict__ w4, const float* __restrict__ b4,
    float* __restrict__ feats, int ibase)
{
    __shared__ __align__(16) float st[16][320];
    __shared__ float w4s[8][16][32];
    int b = blockIdx.x >> 1, h = blockIdx.x & 1;
    int tid = threadIdx.x;
    for (int i = tid; i < 8 * 16 * 32; i += 256) ((float*)w4s)[i] = w4[h * 4096 + i];
    const float* c3b = c3 + (size_t)b * 16 * 260;
    for (int q = tid; q < 16 * 72; q += 256) {
        int ci = q / 72, p4 = q - ci * 72;
        float4 v = ld4_guard(c3b + (size_t)ci * 260, 4 * p4 - 16, 257);
        *(float4*)&st[ci][pmap(4 * p4)] = v;
    }
    __syncthreads();
    for (int q = tid; q < 520; q += 256) {
        int co_l = q / 65, l4 = q - co_l * 65;
        int co = h * 8 + co_l;
        float acc = b4[co];
#pragma unroll 1
        for (int ci = 0; ci < 16; ++ci) {
#pragma unroll
            for (int k4 = 0; k4 < 8; ++k4) {
                float4 v = *(const float4*)&st[ci][pmap(4 * l4 + 4 * k4)];
                const float* wk = &w4s[co_l][ci][4 * k4];
                acc += v.x * wk[0] + v.y * wk[1] + v.z * wk[2] + v.w * wk[3];
            }
        }
        feats[(size_t)(b & 31) * 2080 + (size_t)((b >> 5) + ibase) * 1040 + co * 65 + l4]
            = tanhf(acc);
    }
}

// =====================================================================
// fused fc1+fc2: one block per batch (32 blocks, 512 threads).
// fc1: wave w computes j = w*16..w*16+15 (wave-reduce over 2080);
// h1 in LDS; fc2: wave w computes j2 = 2w, 2w+1.
// =====================================================================
__global__ __launch_bounds__(512) void fc12_kernel(const float* __restrict__ feats,
                                                   const float* __restrict__ w1,
                                                   const float* __restrict__ b1,
                                                   const float* __restrict__ w2,
                                                   const float* __restrict__ b2,
                                                   float* __restrict__ out)
{
    __shared__ float h1s[128];
    int b = blockIdx.x;
    int tid = threadIdx.x, lane = tid & 63, w = tid >> 6;
    const float4* h4 = (const float4*)(feats + (size_t)b * 2080);

#pragma unroll 1
    for (int jj = 0; jj < 16; ++jj) {
        int j = w * 16 + jj;
        const float4* w4 = (const float4*)(w1 + (size_t)j * 2080);
        float acc = 0.f;
#pragma unroll
        for (int q = 0; q < 8; ++q) {
            float4 a = h4[lane + 64 * q], c = w4[lane + 64 * q];
            acc += a.x * c.x + a.y * c.y + a.z * c.z + a.w * c.w;
        }
        if (lane < 8) {
            float4 a = h4[512 + lane], c = w4[512 + lane];
            acc += a.x * c.x + a.y * c.y + a.z * c.z + a.w * c.w;
        }
        for (int off = 32; off; off >>= 1) acc += __shfl_down(acc, off, 64);
        if (lane == 0) h1s[j] = tanhf(acc + b1[j]);
    }
    __syncthreads();

#pragma unroll
    for (int r = 0; r < 2; ++r) {
        int j2 = w * 2 + r;
        const float* wj = w2 + (size_t)j2 * 128;
        float acc = h1s[lane] * wj[lane] + h1s[lane + 64] * wj[lane + 64];
        for (int off = 32; off; off >>= 1) acc += __shfl_down(acc, off, 64);
        if (lane == 0) out[b * 16 + j2] = tanhf(acc + b2[j2]);
    }
}

extern "C" void kernel_launch(void* const* d_in, const int* in_sizes, int n_in,
                              void* d_out, int out_size, void* d_ws, size_t ws_size,
                              hipStream_t stream)
{
    const float* x = (const float*)d_in[0];
    const int* orderings = (const int*)d_in[1];
    const float* sp_w = (const float*)d_in[2];
    const float* sp_b = (const float*)d_in[3];
    const float* conv_w[5];
    const float* conv_b[5];
    for (int j = 0; j < 5; ++j) {
        conv_w[j] = (const float*)d_in[4 + 2 * j];
        conv_b[j] = (const float*)d_in[5 + 2 * j];
    }
    const float* fc1_w = (const float*)d_in[14];
    const float* fc1_b = (const float*)d_in[15];
    const float* fc2_w = (const float*)d_in[16];
    const float* fc2_b = (const float*)d_in[17];

    float* ws = (float*)d_ws;

    if (ws_size >= 12583936ull * 4ull) {
        // ---------- big path: merged B=64, 50.34 MB ----------
        // c0 [0, 4,195,328) over dead xt ; s [4,195,328, 12,583,936) ;
        // c1 [4,195,328, 6,294,528) over dead s ; c2 [6,294,528, 7,347,200) ;
        // c3 [7,347,200, 7,613,440) ; f [7,613,440, 7,680,000).
        size_t o_xt = 0, o_c0 = 0, o_s = 4195328;
        size_t o_c1 = 4195328, o_c2 = 6294528, o_c3 = 7347200, o_f = 7613440;

        transpose_kernel<<<NPTS / 64, 256, 0, stream>>>(x, ws + o_xt);
        smooth2_kernel<<<1024, 256, 0, stream>>>(ws + o_xt, orderings, sp_w, sp_b,
                                                 ws + o_s);
        conv0_wpc<<<64 * 33, 256, 0, stream>>>(ws + o_s, conv_w[0], conv_b[0], ws + o_c0);
        conv1_wpc<<<64 * 17, 256, 0, stream>>>(ws + o_c0, conv_w[1], conv_b[1], ws + o_c1);
        conv2_wpc<<<64 * 9, 256, 0, stream>>>(ws + o_c1, conv_w[2], conv_b[2], ws + o_c2);
        conv3_wpc<<<64 * 5, 256, 0, stream>>>(ws + o_c2, conv_w[3], conv_b[3], ws + o_c3);
        conv4_kernel<<<128, 256, 0, stream>>>(ws + o_c3, conv_w[4], conv_b[4],
                                              ws + o_f, 0);
        fc12_kernel<<<32, 512, 0, stream>>>(ws + o_f, fc1_w, fc1_b, fc2_w, fc2_b,
                                            (float*)d_out);
    } else {
        // ---------- small path: per-SFC, 42.2 MB ----------
        size_t o_xt = 0, o_s = 4194304, o_c0 = 8388608;
        size_t o_c1 = 4194304, o_c2 = 5243904, o_c3 = 5770240, o_f = 10486272;

        transpose_kernel<<<NPTS / 64, 256, 0, stream>>>(x, ws + o_xt);
        for (int i = 0; i < 2; ++i) {
            smooth2_kernel<<<512, 256, 0, stream>>>(ws + o_xt,
                                                    orderings + (size_t)i * NPTS,
                                                    sp_w, sp_b, ws + o_s);
            conv0_wpc<<<32 * 33, 256, 0, stream>>>(ws + o_s, conv_w[0], conv_b[0], ws + o_c0);
            conv1_wpc<<<32 * 17, 256, 0, stream>>>(ws + o_c0, conv_w[1], conv_b[1], ws + o_c1);
            conv2_wpc<<<32 * 9, 256, 0, stream>>>(ws + o_c1, conv_w[2], conv_b[2], ws + o_c2);
            conv3_wpc<<<32 * 5, 256, 0, stream>>>(ws + o_c2, conv_w[3], conv_b[3], ws + o_c3);
            conv4_kernel<<<64, 256, 0, stream>>>(ws + o_c3, conv_w[4], conv_b[4],
                                                 ws + o_f, i);
        }
        fc12_kernel<<<32, 512, 0, stream>>>(ws + o_f, fc1_w, fc1_b, fc2_w, fc2_b,
                                            (float*)d_out);
    }
}

// Round 17
// 144.197 us; speedup vs baseline: 1.0170x; 1.0170x over previous
//
#include <hip/hip_runtime.h>
#include <math.h>

#define NPTS 65536

__device__ __forceinline__ float4 ld4_guard(const float* __restrict__ row, int pos, int hi) {
    float4 v;
    if (pos >= 0 && pos + 4 <= hi) {
        v = *(const float4*)(row + pos);
    } else {
        v.x = (pos + 0 >= 0 && pos + 0 < hi) ? row[pos + 0] : 0.f;
        v.y = (pos + 1 >= 0 && pos + 1 < hi) ? row[pos + 1] : 0.f;
        v.z = (pos + 2 >= 0 && pos + 2 < hi) ? row[pos + 2] : 0.f;
        v.w = (pos + 3 >= 0 && pos + 3 < hi) ? row[pos + 3] : 0.f;
    }
    return v;
}

// pad 4 floats every 32: breaks 128B-stride aliasing, float4-safe.
__device__ __forceinline__ int pmap(int p) { return p + ((p >> 5) << 2); }

// =====================================================================
// transpose x (B,N,2) -> x_t (N, 64)
// =====================================================================
__global__ __launch_bounds__(256) void transpose_kernel(const float* __restrict__ x,
                                                        float* __restrict__ xt)
{
    __shared__ float tile[64][65];
    int n0 = blockIdx.x * 64;
    int tid = threadIdx.x;
    int lane = tid & 63, w = tid >> 6;
    const float2* x2 = (const float2*)x;
#pragma unroll
    for (int bq = 0; bq < 8; ++bq) {
        int b = bq * 4 + w;
        float2 v = x2[(size_t)b * NPTS + n0 + lane];
        tile[lane][b * 2 + 0] = v.x;
        tile[lane][b * 2 + 1] = v.y;
    }
    __syncthreads();
    int f4 = tid & 15;
#pragma unroll
    for (int rq = 0; rq < 4; ++rq) {
        int r = rq * 16 + (tid >> 4);
        float4 v = make_float4(tile[r][f4 * 4 + 0], tile[r][f4 * 4 + 1],
                               tile[r][f4 * 4 + 2], tile[r][f4 * 4 + 3]);
        *(float4*)&xt[(size_t)(n0 + r) * 64 + f4 * 4] = v;
    }
}

// =====================================================================
// smooth, both SFC in one launch: i = bid>>9, tile t = bid&511.
// s_out: s0 + i*4194304 + (b*2+c)*N + n   (fp32)
// =====================================================================
__global__ __launch_bounds__(256) void smooth2_kernel(const float* __restrict__ xt,
                                                      const int* __restrict__ ord0,
                                                      const float* __restrict__ sp_w,
                                                      const float* __restrict__ sp_b,
                                                      float* __restrict__ s0)
{
    __shared__ int s_idx[130];
    __shared__ float rows[130][65];
    int bid = blockIdx.x;
    int i = bid >> 9;
    int t = bid & 511;
    const int* ord = ord0 + (size_t)i * NPTS;
    float* s = s0 + (size_t)i * 4194304;
    int n0 = t * 128;
    int tid = threadIdx.x;
    if (tid < 130) {
        int g = n0 - 1 + tid;
        g = g < 0 ? 0 : (g > NPTS - 1 ? NPTS - 1 : g);
        s_idx[tid] = ord[g];
    }
    __syncthreads();
    for (int q = tid; q < 130 * 16; q += 256) {
        int r = q >> 4, f4 = q & 15;
        float4 v = *(const float4*)&xt[(size_t)s_idx[r] * 64 + f4 * 4];
        rows[r][f4 * 4 + 0] = v.x; rows[r][f4 * 4 + 1] = v.y;
        rows[r][f4 * 4 + 2] = v.z; rows[r][f4 * 4 + 3] = v.w;
    }
    __syncthreads();
    int n_local = tid & 127, half = tid >> 7;
    int n = n0 + n_local;
    float w0 = sp_w[n * 3 + 0], w1 = sp_w[n * 3 + 1], w2 = sp_w[n * 3 + 2];
    float bb = sp_b[n];
#pragma unroll 4
    for (int bc = 0; bc < 64; bc += 2) {
        int bce = bc + half;
        float v = w0 * rows[n_local][bce] + w1 * rows[n_local + 1][bce]
                + w2 * rows[n_local + 2][bce] + bb;
        s[(size_t)bce * NPTS + n] = tanhf(v);
    }
}

// =====================================================================
// conv0 wave-per-co: 4 waves = 4 co; lane owns 8 consecutive l.
// =====================================================================
__global__ __launch_bounds__(256, 2) void conv0_wpc(
    const float* __restrict__ in,      // s: rows (b*2+ci)*NPTS
    const float* __restrict__ w,       // (4,2,32)
    const float* __restrict__ bias,
    float* __restrict__ out)           // (B,4,16388), valid l<16385
{
    constexpr int SPAN = 2076;
    __shared__ float in_s[2][2336];

    int bid = blockIdx.x;
    int tile = bid % 33;
    int b = bid / 33;
    int tid = threadIdx.x;

    int base = tile * 2048 - 16;
    const float* inb = in + (size_t)b * 2 * NPTS;
    for (int q = tid; q < 2 * (SPAN / 4); q += 256) {
        int ci = q / (SPAN / 4), fp = q - ci * (SPAN / 4);
        int p = 4 * fp;
        float4 v = ld4_guard(inb + (size_t)ci * NPTS, base + p, NPTS);
        *(float4*)&in_s[ci][pmap(p)] = v;
    }
    __syncthreads();

    int lane = tid & 63;
    int co_u = __builtin_amdgcn_readfirstlane(tid >> 6);

    float acc[8];
    float bv = bias[co_u];
#pragma unroll
    for (int j = 0; j < 8; ++j) acc[j] = bv;

#pragma unroll 1
    for (int ci = 0; ci < 2; ++ci) {
        const float* wb = w + (co_u * 2 + ci) * 32;
        float wv[32];
#pragma unroll
        for (int k = 0; k < 32; ++k) wv[k] = wb[k];
        float4 v[15];
#pragma unroll
        for (int k = 0; k < 15; ++k)
            v[k] = *(const float4*)&in_s[ci][pmap(32 * lane + 4 * k)];
#pragma unroll
        for (int k4 = 0; k4 < 8; ++k4) {
            float wx = wv[4 * k4], wy = wv[4 * k4 + 1], wz = wv[4 * k4 + 2], ww = wv[4 * k4 + 3];
#pragma unroll
            for (int j = 0; j < 8; ++j)
                acc[j] += v[j + k4].x * wx + v[j + k4].y * wy
                        + v[j + k4].z * wz + v[j + k4].w * ww;
        }
    }

    int l0 = tile * 512 + lane * 8;
    size_t row = ((size_t)b * 4 + co_u) * 16388;
    if (l0 + 8 <= 16385) {
        float4 s0 = make_float4(tanhf(acc[0]), tanhf(acc[1]), tanhf(acc[2]), tanhf(acc[3]));
        float4 s1 = make_float4(tanhf(acc[4]), tanhf(acc[5]), tanhf(acc[6]), tanhf(acc[7]));
        *(float4*)&out[row + l0] = s0;
        *(float4*)&out[row + l0 + 4] = s1;
    } else {
#pragma unroll
        for (int j = 0; j < 8; ++j)
            if (l0 + j < 16385) out[row + l0 + j] = tanhf(acc[j]);
    }
}

// =====================================================================
// conv1 wave-per-co (512 thr): 8 waves = 8 co; lane owns 4 consecutive l.
// =====================================================================
__global__ __launch_bounds__(512) void conv1_wpc(
    const float* __restrict__ in,      // c0 (B,4,16388), valid 16385
    const float* __restrict__ w,       // (8,4,32)
    const float* __restrict__ bias,
    float* __restrict__ out)           // (B,8,4100), valid l<4097
{
    constexpr int SPAN = 1052;
    __shared__ float in_s[4][1184];

    int bid = blockIdx.x;
    int tile = bid % 17;
    int b = bid / 17;
    int tid = threadIdx.x;

    int base = tile * 1024 - 16;
    const float* inb = in + (size_t)b * 4 * 16388;
    for (int q = tid; q < 4 * (SPAN / 4); q += 512) {
        int ci = q / (SPAN / 4), fp = q - ci * (SPAN / 4);
        int p = 4 * fp;
        float4 v = ld4_guard(inb + (size_t)ci * 16388, base + p, 16385);
        *(float4*)&in_s[ci][pmap(p)] = v;
    }
    __syncthreads();

    int lane = tid & 63;
    int co_u = __builtin_amdgcn_readfirstlane(tid >> 6);

    float acc[4];
    float bv = bias[co_u];
#pragma unroll
    for (int j = 0; j < 4; ++j) acc[j] = bv;

#pragma unroll 1
    for (int ci = 0; ci < 4; ++ci) {
        const float* wb = w + (size_t)(co_u * 4 + ci) * 32;
        float wv[32];
#pragma unroll
        for (int k = 0; k < 32; ++k) wv[k] = wb[k];
        float4 v[11];
#pragma unroll
        for (int k = 0; k < 11; ++k)
            v[k] = *(const float4*)&in_s[ci][pmap(16 * lane + 4 * k)];
#pragma unroll
        for (int k4 = 0; k4 < 8; ++k4) {
            float wx = wv[4 * k4], wy = wv[4 * k4 + 1], wz = wv[4 * k4 + 2], ww = wv[4 * k4 + 3];
#pragma unroll
            for (int j = 0; j < 4; ++j)
                acc[j] += v[j + k4].x * wx + v[j + k4].y * wy
                        + v[j + k4].z * wz + v[j + k4].w * ww;
        }
    }

    int l0 = tile * 256 + lane * 4;
    size_t row = ((size_t)b * 8 + co_u) * 4100;
    if (l0 + 4 <= 4097) {
        float4 s0 = make_float4(tanhf(acc[0]), tanhf(acc[1]), tanhf(acc[2]), tanhf(acc[3]));
        *(float4*)&out[row + l0] = s0;
    } else {
#pragma unroll
        for (int j = 0; j < 4; ++j)
            if (l0 + j < 4097) out[row + l0 + j] = tanhf(acc[j]);
    }
}

// =====================================================================
// conv2 wave-per-co-pair (512 thr): 8 waves own {w, w+8}; lane owns 2 l.
// =====================================================================
__global__ __launch_bounds__(512) void conv2_wpc(
    const float* __restrict__ in,      // c1 (B,8,4100), valid 4097
    const float* __restrict__ w,       // (16,8,32)
    const float* __restrict__ bias,
    float* __restrict__ out)           // (B,16,1028), valid l<1025
{
    constexpr int SPAN = 540;
    __shared__ float in_s[8][608];

    int bid = blockIdx.x;
    int tile = bid % 9;
    int b = bid / 9;
    int tid = threadIdx.x;

    int base = tile * 512 - 16;
    const float* inb = in + (size_t)b * 8 * 4100;
    for (int q = tid; q < 8 * (SPAN / 4); q += 512) {
        int ci = q / (SPAN / 4), fp = q - ci * (SPAN / 4);
        int p = 4 * fp;
        float4 v = ld4_guard(inb + (size_t)ci * 4100, base + p, 4097);
        *(float4*)&in_s[ci][pmap(p)] = v;
    }
    __syncthreads();

    int lane = tid & 63;
    int co_u = __builtin_amdgcn_readfirstlane(tid >> 6);   // 0..7

    float acc[2][2];
    acc[0][0] = acc[0][1] = bias[co_u];
    acc[1][0] = acc[1][1] = bias[co_u + 8];

#pragma unroll 1
    for (int ci = 0; ci < 8; ++ci) {
        const float* wa = w + (size_t)(co_u * 8 + ci) * 32;
        const float* wb = w + (size_t)((co_u + 8) * 8 + ci) * 32;
        float4 v[9];
#pragma unroll
        for (int k = 0; k < 9; ++k)
            v[k] = *(const float4*)&in_s[ci][pmap(8 * lane + 4 * k)];
#pragma unroll
        for (int k4 = 0; k4 < 8; ++k4) {
            float4 wva = *(const float4*)(wa + 4 * k4);
            float4 wvb = *(const float4*)(wb + 4 * k4);
#pragma unroll
            for (int j = 0; j < 2; ++j) {
                acc[0][j] += v[k4 + j].x * wva.x + v[k4 + j].y * wva.y
                           + v[k4 + j].z * wva.z + v[k4 + j].w * wva.w;
                acc[1][j] += v[k4 + j].x * wvb.x + v[k4 + j].y * wvb.y
                           + v[k4 + j].z * wvb.z + v[k4 + j].w * wvb.w;
            }
        }
    }

    int l0 = tile * 128 + lane * 2;
#pragma unroll
    for (int h = 0; h < 2; ++h) {
        size_t row = ((size_t)b * 16 + co_u + 8 * h) * 1028;
        if (l0 + 2 <= 1025) {
            float2 st2 = make_float2(tanhf(acc[h][0]), tanhf(acc[h][1]));
            *(float2*)&out[row + l0] = st2;
        } else {
#pragma unroll
            for (int j = 0; j < 2; ++j)
                if (l0 + j < 1025) out[row + l0 + j] = tanhf(acc[h][j]);
        }
    }
}

// =====================================================================
// conv3 wave-per-co-pair (512 thr): 8 waves own {w, w+8}; lane owns 1 l.
// =====================================================================
__global__ __launch_bounds__(512) void conv3_wpc(
    const float* __restrict__ in,      // c2 (B,16,1028), valid 1025
    const float* __restrict__ w,       // (16,16,32)
    const float* __restrict__ bias,
    float* __restrict__ out)           // (B,16,260), valid l<257
{
    constexpr int SPAN = 284;
    __shared__ float in_s[16][320];

    int bid = blockIdx.x;
    int tile = bid % 5;
    int b = bid / 5;
    int tid = threadIdx.x;

    int base = tile * 256 - 16;
    const float* inb = in + (size_t)b * 16 * 1028;
    for (int q = tid; q < 16 * (SPAN / 4); q += 512) {
        int ci = q / (SPAN / 4), fp = q - ci * (SPAN / 4);
        int p = 4 * fp;
        float4 v = ld4_guard(inb + (size_t)ci * 1028, base + p, 1025);
        *(float4*)&in_s[ci][pmap(p)] = v;
    }
    __syncthreads();

    int lane = tid & 63;
    int co_u = __builtin_amdgcn_readfirstlane(tid >> 6);   // 0..7

    float acc0 = bias[co_u], acc1 = bias[co_u + 8];

#pragma unroll 1
    for (int ci = 0; ci < 16; ++ci) {
        const float* wa = w + (size_t)(co_u * 16 + ci) * 32;
        const float* wb = w + (size_t)((co_u + 8) * 16 + ci) * 32;
        float4 v[8];
#pragma unroll
        for (int k = 0; k < 8; ++k)
            v[k] = *(const float4*)&in_s[ci][pmap(4 * lane + 4 * k)];
#pragma unroll
        for (int k4 = 0; k4 < 8; ++k4) {
            float4 wva = *(const float4*)(wa + 4 * k4);
            float4 wvb = *(const float4*)(wb + 4 * k4);
            acc0 += v[k4].x * wva.x + v[k4].y * wva.y
                  + v[k4].z * wva.z + v[k4].w * wva.w;
            acc1 += v[k4].x * wvb.x + v[k4].y * wvb.y
                  + v[k4].z * wvb.z + v[k4].w * wvb.w;
        }
    }

    int l3 = tile * 64 + lane;
    if (l3 < 257) {
        out[((size_t)b * 16 + co_u) * 260 + l3] = tanhf(acc0);
        out[((size_t)b * 16 + co_u + 8) * 260 + l3] = tanhf(acc1);
    }
}

// =====================================================================
// conv4 + concat into feats. Block = (b, co-half), pmap-padded st.
// =====================================================================
__global__ __launch_bounds__(256) void conv4_kernel(
    const float* __restrict__ c3,      // (B, 16, 260), valid l3 < 257
    const float* __restrict__ w4, const float* __restrict__ b4,
    float* __restrict__ feats, int ibase)
{
    __shared__ __align__(16) float st[16][320];
    __shared__ float w4s[8][16][32];
    int b = blockIdx.x >> 1, h = blockIdx.x & 1;
    int tid = threadIdx.x;
    for (int i = tid; i < 8 * 16 * 32; i += 256) ((float*)w4s)[i] = w4[h * 4096 + i];
    const float* c3b = c3 + (size_t)b * 16 * 260;
    for (int q = tid; q < 16 * 72; q += 256) {
        int ci = q / 72, p4 = q - ci * 72;
        float4 v = ld4_guard(c3b + (size_t)ci * 260, 4 * p4 - 16, 257);
        *(float4*)&st[ci][pmap(4 * p4)] = v;
    }
    __syncthreads();
    for (int q = tid; q < 520; q += 256) {
        int co_l = q / 65, l4 = q - co_l * 65;
        int co = h * 8 + co_l;
        float acc = b4[co];
#pragma unroll 1
        for (int ci = 0; ci < 16; ++ci) {
#pragma unroll
            for (int k4 = 0; k4 < 8; ++k4) {
                float4 v = *(const float4*)&st[ci][pmap(4 * l4 + 4 * k4)];
                const float* wk = &w4s[co_l][ci][4 * k4];
                acc += v.x * wk[0] + v.y * wk[1] + v.z * wk[2] + v.w * wk[3];
            }
        }
        feats[(size_t)(b & 31) * 2080 + (size_t)((b >> 5) + ibase) * 1040 + co * 65 + l4]
            = tanhf(acc);
    }
}

// =====================================================================
// fused fc1+fc2: one block per batch (32 blocks, 512 threads).
// fc1: wave w computes j = w*16..w*16+15 (wave-reduce over 2080);
// h1 in LDS; fc2: wave w computes j2 = 2w, 2w+1.
// =====================================================================
__global__ __launch_bounds__(512) void fc12_kernel(const float* __restrict__ feats,
                                                   const float* __restrict__ w1,
                                                   const float* __restrict__ b1,
                                                   const float* __restrict__ w2,
                                                   const float* __restrict__ b2,
                                                   float* __restrict__ out)
{
    __shared__ float h1s[128];
    int b = blockIdx.x;
    int tid = threadIdx.x, lane = tid & 63, w = tid >> 6;
    const float4* h4 = (const float4*)(feats + (size_t)b * 2080);

#pragma unroll 1
    for (int jj = 0; jj < 16; ++jj) {
        int j = w * 16 + jj;
        const float4* w4 = (const float4*)(w1 + (size_t)j * 2080);
        float acc = 0.f;
#pragma unroll
        for (int q = 0; q < 8; ++q) {
            float4 a = h4[lane + 64 * q], c = w4[lane + 64 * q];
            acc += a.x * c.x + a.y * c.y + a.z * c.z + a.w * c.w;
        }
        if (lane < 8) {
            float4 a = h4[512 + lane], c = w4[512 + lane];
            acc += a.x * c.x + a.y * c.y + a.z * c.z + a.w * c.w;
        }
        for (int off = 32; off; off >>= 1) acc += __shfl_down(acc, off, 64);
        if (lane == 0) h1s[j] = tanhf(acc + b1[j]);
    }
    __syncthreads();

#pragma unroll
    for (int r = 0; r < 2; ++r) {
        int j2 = w * 2 + r;
        const float* wj = w2 + (size_t)j2 * 128;
        float acc = h1s[lane] * wj[lane] + h1s[lane + 64] * wj[lane + 64];
        for (int off = 32; off; off >>= 1) acc += __shfl_down(acc, off, 64);
        if (lane == 0) out[b * 16 + j2] = tanhf(acc + b2[j2]);
    }
}

extern "C" void kernel_launch(void* const* d_in, const int* in_sizes, int n_in,
                              void* d_out, int out_size, void* d_ws, size_t ws_size,
                              hipStream_t stream)
{
    const float* x = (const float*)d_in[0];
    const int* orderings = (const int*)d_in[1];
    const float* sp_w = (const float*)d_in[2];
    const float* sp_b = (const float*)d_in[3];
    const float* conv_w[5];
    const float* conv_b[5];
    for (int j = 0; j < 5; ++j) {
        conv_w[j] = (const float*)d_in[4 + 2 * j];
        conv_b[j] = (const float*)d_in[5 + 2 * j];
    }
    const float* fc1_w = (const float*)d_in[14];
    const float* fc1_b = (const float*)d_in[15];
    const float* fc2_w = (const float*)d_in[16];
    const float* fc2_b = (const float*)d_in[17];

    float* ws = (float*)d_ws;

    if (ws_size >= 12583936ull * 4ull) {
        // ---------- big path: merged B=64, 50.34 MB ----------
        // c0 [0, 4,195,328) over dead xt ; s [4,195,328, 12,583,936) ;
        // c1 [4,195,328, 6,294,528) over dead s ; c2 [6,294,528, 7,347,200) ;
        // c3 [7,347,200, 7,613,440) ; f [7,613,440, 7,680,000).
        size_t o_xt = 0, o_c0 = 0, o_s = 4195328;
        size_t o_c1 = 4195328, o_c2 = 6294528, o_c3 = 7347200, o_f = 7613440;

        transpose_kernel<<<NPTS / 64, 256, 0, stream>>>(x, ws + o_xt);
        smooth2_kernel<<<1024, 256, 0, stream>>>(ws + o_xt, orderings, sp_w, sp_b,
                                                 ws + o_s);
        conv0_wpc<<<64 * 33, 256, 0, stream>>>(ws + o_s, conv_w[0], conv_b[0], ws + o_c0);
        conv1_wpc<<<64 * 17, 512, 0, stream>>>(ws + o_c0, conv_w[1], conv_b[1], ws + o_c1);
        conv2_wpc<<<64 * 9, 512, 0, stream>>>(ws + o_c1, conv_w[2], conv_b[2], ws + o_c2);
        conv3_wpc<<<64 * 5, 512, 0, stream>>>(ws + o_c2, conv_w[3], conv_b[3], ws + o_c3);
        conv4_kernel<<<128, 256, 0, stream>>>(ws + o_c3, conv_w[4], conv_b[4],
                                              ws + o_f, 0);
        fc12_kernel<<<32, 512, 0, stream>>>(ws + o_f, fc1_w, fc1_b, fc2_w, fc2_b,
                                            (float*)d_out);
    } else {
        // ---------- small path: per-SFC, 42.2 MB ----------
        // xt [0,4.19M) ; s [4.19M, 8.39M) ; c0 [8.39M, 10,486,272) ;
        // c1 [4,194,304, 5,243,904) over dead s ; c2 [5,243,904, 5,770,240) ;
        // c3 [5,770,240, 5,903,360) ; f [10,486,272, 10,552,832).
        size_t o_xt = 0, o_s = 4194304, o_c0 = 8388608;
        size_t o_c1 = 4194304, o_c2 = 5243904, o_c3 = 5770240, o_f = 10486272;

        transpose_kernel<<<NPTS / 64, 256, 0, stream>>>(x, ws + o_xt);
        for (int i = 0; i < 2; ++i) {
            smooth2_kernel<<<512, 256, 0, stream>>>(ws + o_xt,
                                                    orderings + (size_t)i * NPTS,
                                                    sp_w, sp_b, ws + o_s);
            conv0_wpc<<<32 * 33, 256, 0, stream>>>(ws + o_s, conv_w[0], conv_b[0], ws + o_c0);
            conv1_wpc<<<32 * 17, 512, 0, stream>>>(ws + o_c0, conv_w[1], conv_b[1], ws + o_c1);
            conv2_wpc<<<32 * 9, 512, 0, stream>>>(ws + o_c1, conv_w[2], conv_b[2], ws + o_c2);
            conv3_wpc<<<32 * 5, 512, 0, stream>>>(ws + o_c2, conv_w[3], conv_b[3], ws + o_c3);
            conv4_kernel<<<64, 256, 0, stream>>>(ws + o_c3, conv_w[4], conv_b[4],
                                                 ws + o_f, i);
        }
        fc12_kernel<<<32, 512, 0, stream>>>(ws + o_f, fc1_w, fc1_b, fc2_w, fc2_b,
                                            (float*)d_out);
    }
}

// Round 18
// 138.566 us; speedup vs baseline: 1.0583x; 1.0406x over previous
//
#include <hip/hip_runtime.h>
#include <math.h>

#define NPTS 65536

__device__ __forceinline__ float4 ld4_guard(const float* __restrict__ row, int pos, int hi) {
    float4 v;
    if (pos >= 0 && pos + 4 <= hi) {
        v = *(const float4*)(row + pos);
    } else {
        v.x = (pos + 0 >= 0 && pos + 0 < hi) ? row[pos + 0] : 0.f;
        v.y = (pos + 1 >= 0 && pos + 1 < hi) ? row[pos + 1] : 0.f;
        v.z = (pos + 2 >= 0 && pos + 2 < hi) ? row[pos + 2] : 0.f;
        v.w = (pos + 3 >= 0 && pos + 3 < hi) ? row[pos + 3] : 0.f;
    }
    return v;
}

// pad 4 floats every 32: breaks 128B-stride aliasing, float4-safe.
__device__ __forceinline__ int pmap(int p) { return p + ((p >> 5) << 2); }

// =====================================================================
// transpose x (B,N,2) -> x_t (N, 64)
// =====================================================================
__global__ __launch_bounds__(256) void transpose_kernel(const float* __restrict__ x,
                                                        float* __restrict__ xt)
{
    __shared__ float tile[64][65];
    int n0 = blockIdx.x * 64;
    int tid = threadIdx.x;
    int lane = tid & 63, w = tid >> 6;
    const float2* x2 = (const float2*)x;
#pragma unroll
    for (int bq = 0; bq < 8; ++bq) {
        int b = bq * 4 + w;
        float2 v = x2[(size_t)b * NPTS + n0 + lane];
        tile[lane][b * 2 + 0] = v.x;
        tile[lane][b * 2 + 1] = v.y;
    }
    __syncthreads();
    int f4 = tid & 15;
#pragma unroll
    for (int rq = 0; rq < 4; ++rq) {
        int r = rq * 16 + (tid >> 4);
        float4 v = make_float4(tile[r][f4 * 4 + 0], tile[r][f4 * 4 + 1],
                               tile[r][f4 * 4 + 2], tile[r][f4 * 4 + 3]);
        *(float4*)&xt[(size_t)(n0 + r) * 64 + f4 * 4] = v;
    }
}

// =====================================================================
// smooth (one SFC): s[(b*2+c)*N + n] = tanh(...). Full-row 256B gather.
// =====================================================================
__global__ __launch_bounds__(256) void smooth_kernel(const float* __restrict__ xt,
                                                     const int* __restrict__ ord,
                                                     const float* __restrict__ sp_w,
                                                     const float* __restrict__ sp_b,
                                                     float* __restrict__ s)
{
    __shared__ int s_idx[130];
    __shared__ float rows[130][65];
    int n0 = blockIdx.x * 128;
    int tid = threadIdx.x;
    if (tid < 130) {
        int g = n0 - 1 + tid;
        g = g < 0 ? 0 : (g > NPTS - 1 ? NPTS - 1 : g);
        s_idx[tid] = ord[g];
    }
    __syncthreads();
    for (int q = tid; q < 130 * 16; q += 256) {
        int r = q >> 4, f4 = q & 15;
        float4 v = *(const float4*)&xt[(size_t)s_idx[r] * 64 + f4 * 4];
        rows[r][f4 * 4 + 0] = v.x; rows[r][f4 * 4 + 1] = v.y;
        rows[r][f4 * 4 + 2] = v.z; rows[r][f4 * 4 + 3] = v.w;
    }
    __syncthreads();
    int n_local = tid & 127, half = tid >> 7;
    int n = n0 + n_local;
    float w0 = sp_w[n * 3 + 0], w1 = sp_w[n * 3 + 1], w2 = sp_w[n * 3 + 2];
    float bb = sp_b[n];
#pragma unroll 4
    for (int bc = 0; bc < 64; bc += 2) {
        int bce = bc + half;
        float v = w0 * rows[n_local][bce] + w1 * rows[n_local + 1][bce]
                + w2 * rows[n_local + 2][bce] + bb;
        s[(size_t)bce * NPTS + n] = tanhf(v);
    }
}

// =====================================================================
// conv0 wave-per-co: 4 waves = 4 co; lane owns 8 consecutive l.
// =====================================================================
__global__ __launch_bounds__(256, 2) void conv0_wpc(
    const float* __restrict__ in,      // s: rows (b*2+ci)*NPTS
    const float* __restrict__ w,       // (4,2,32)
    const float* __restrict__ bias,
    float* __restrict__ out)           // (B,4,16388), valid l<16385
{
    constexpr int SPAN = 2076;
    __shared__ float in_s[2][2336];

    int bid = blockIdx.x;
    int tile = bid % 33;
    int b = bid / 33;
    int tid = threadIdx.x;

    int base = tile * 2048 - 16;
    const float* inb = in + (size_t)b * 2 * NPTS;
    for (int q = tid; q < 2 * (SPAN / 4); q += 256) {
        int ci = q / (SPAN / 4), fp = q - ci * (SPAN / 4);
        int p = 4 * fp;
        float4 v = ld4_guard(inb + (size_t)ci * NPTS, base + p, NPTS);
        *(float4*)&in_s[ci][pmap(p)] = v;
    }
    __syncthreads();

    int lane = tid & 63;
    int co_u = __builtin_amdgcn_readfirstlane(tid >> 6);

    float acc[8];
    float bv = bias[co_u];
#pragma unroll
    for (int j = 0; j < 8; ++j) acc[j] = bv;

#pragma unroll 1
    for (int ci = 0; ci < 2; ++ci) {
        const float* wb = w + (co_u * 2 + ci) * 32;
        float wv[32];
#pragma unroll
        for (int k = 0; k < 32; ++k) wv[k] = wb[k];
        float4 v[15];
#pragma unroll
        for (int k = 0; k < 15; ++k)
            v[k] = *(const float4*)&in_s[ci][pmap(32 * lane + 4 * k)];
#pragma unroll
        for (int k4 = 0; k4 < 8; ++k4) {
            float wx = wv[4 * k4], wy = wv[4 * k4 + 1], wz = wv[4 * k4 + 2], ww = wv[4 * k4 + 3];
#pragma unroll
            for (int j = 0; j < 8; ++j)
                acc[j] += v[j + k4].x * wx + v[j + k4].y * wy
                        + v[j + k4].z * wz + v[j + k4].w * ww;
        }
    }

    int l0 = tile * 512 + lane * 8;
    size_t row = ((size_t)b * 4 + co_u) * 16388;
    if (l0 + 8 <= 16385) {
        float4 s0 = make_float4(tanhf(acc[0]), tanhf(acc[1]), tanhf(acc[2]), tanhf(acc[3]));
        float4 s1 = make_float4(tanhf(acc[4]), tanhf(acc[5]), tanhf(acc[6]), tanhf(acc[7]));
        *(float4*)&out[row + l0] = s0;
        *(float4*)&out[row + l0 + 4] = s1;
    } else {
#pragma unroll
        for (int j = 0; j < 8; ++j)
            if (l0 + j < 16385) out[row + l0 + j] = tanhf(acc[j]);
    }
}

// =====================================================================
// conv1 wave-per-co (512 thr): 8 waves = 8 co; lane owns 4 consecutive l.
// =====================================================================
__global__ __launch_bounds__(512) void conv1_wpc(
    const float* __restrict__ in,      // c0 (B,4,16388), valid 16385
    const float* __restrict__ w,       // (8,4,32)
    const float* __restrict__ bias,
    float* __restrict__ out)           // (B,8,4100), valid l<4097
{
    constexpr int SPAN = 1052;
    __shared__ float in_s[4][1184];

    int bid = blockIdx.x;
    int tile = bid % 17;
    int b = bid / 17;
    int tid = threadIdx.x;

    int base = tile * 1024 - 16;
    const float* inb = in + (size_t)b * 4 * 16388;
    for (int q = tid; q < 4 * (SPAN / 4); q += 512) {
        int ci = q / (SPAN / 4), fp = q - ci * (SPAN / 4);
        int p = 4 * fp;
        float4 v = ld4_guard(inb + (size_t)ci * 16388, base + p, 16385);
        *(float4*)&in_s[ci][pmap(p)] = v;
    }
    __syncthreads();

    int lane = tid & 63;
    int co_u = __builtin_amdgcn_readfirstlane(tid >> 6);

    float acc[4];
    float bv = bias[co_u];
#pragma unroll
    for (int j = 0; j < 4; ++j) acc[j] = bv;

#pragma unroll 1
    for (int ci = 0; ci < 4; ++ci) {
        const float* wb = w + (size_t)(co_u * 4 + ci) * 32;
        float wv[32];
#pragma unroll
        for (int k = 0; k < 32; ++k) wv[k] = wb[k];
        float4 v[11];
#pragma unroll
        for (int k = 0; k < 11; ++k)
            v[k] = *(const float4*)&in_s[ci][pmap(16 * lane + 4 * k)];
#pragma unroll
        for (int k4 = 0; k4 < 8; ++k4) {
            float wx = wv[4 * k4], wy = wv[4 * k4 + 1], wz = wv[4 * k4 + 2], ww = wv[4 * k4 + 3];
#pragma unroll
            for (int j = 0; j < 4; ++j)
                acc[j] += v[j + k4].x * wx + v[j + k4].y * wy
                        + v[j + k4].z * wz + v[j + k4].w * ww;
        }
    }

    int l0 = tile * 256 + lane * 4;
    size_t row = ((size_t)b * 8 + co_u) * 4100;
    if (l0 + 4 <= 4097) {
        float4 s0 = make_float4(tanhf(acc[0]), tanhf(acc[1]), tanhf(acc[2]), tanhf(acc[3]));
        *(float4*)&out[row + l0] = s0;
    } else {
#pragma unroll
        for (int j = 0; j < 4; ++j)
            if (l0 + j < 4097) out[row + l0 + j] = tanhf(acc[j]);
    }
}

// =====================================================================
// conv2 wave-per-co-pair (512 thr): 8 waves own {w, w+8}; lane owns 2 l.
// =====================================================================
__global__ __launch_bounds__(512) void conv2_wpc(
    const float* __restrict__ in,      // c1 (B,8,4100), valid 4097
    const float* __restrict__ w,       // (16,8,32)
    const float* __restrict__ bias,
    float* __restrict__ out)           // (B,16,1028), valid l<1025
{
    constexpr int SPAN = 540;
    __shared__ float in_s[8][608];

    int bid = blockIdx.x;
    int tile = bid % 9;
    int b = bid / 9;
    int tid = threadIdx.x;

    int base = tile * 512 - 16;
    const float* inb = in + (size_t)b * 8 * 4100;
    for (int q = tid; q < 8 * (SPAN / 4); q += 512) {
        int ci = q / (SPAN / 4), fp = q - ci * (SPAN / 4);
        int p = 4 * fp;
        float4 v = ld4_guard(inb + (size_t)ci * 4100, base + p, 4097);
        *(float4*)&in_s[ci][pmap(p)] = v;
    }
    __syncthreads();

    int lane = tid & 63;
    int co_u = __builtin_amdgcn_readfirstlane(tid >> 6);   // 0..7

    float acc[2][2];
    acc[0][0] = acc[0][1] = bias[co_u];
    acc[1][0] = acc[1][1] = bias[co_u + 8];

#pragma unroll 1
    for (int ci = 0; ci < 8; ++ci) {
        const float* wa = w + (size_t)(co_u * 8 + ci) * 32;
        const float* wb = w + (size_t)((co_u + 8) * 8 + ci) * 32;
        float4 v[9];
#pragma unroll
        for (int k = 0; k < 9; ++k)
            v[k] = *(const float4*)&in_s[ci][pmap(8 * lane + 4 * k)];
#pragma unroll
        for (int k4 = 0; k4 < 8; ++k4) {
            float4 wva = *(const float4*)(wa + 4 * k4);
            float4 wvb = *(const float4*)(wb + 4 * k4);
#pragma unroll
            for (int j = 0; j < 2; ++j) {
                acc[0][j] += v[k4 + j].x * wva.x + v[k4 + j].y * wva.y
                           + v[k4 + j].z * wva.z + v[k4 + j].w * wva.w;
                acc[1][j] += v[k4 + j].x * wvb.x + v[k4 + j].y * wvb.y
                           + v[k4 + j].z * wvb.z + v[k4 + j].w * wvb.w;
            }
        }
    }

    int l0 = tile * 128 + lane * 2;
#pragma unroll
    for (int h = 0; h < 2; ++h) {
        size_t row = ((size_t)b * 16 + co_u + 8 * h) * 1028;
        if (l0 + 2 <= 1025) {
            float2 st2 = make_float2(tanhf(acc[h][0]), tanhf(acc[h][1]));
            *(float2*)&out[row + l0] = st2;
        } else {
#pragma unroll
            for (int j = 0; j < 2; ++j)
                if (l0 + j < 1025) out[row + l0 + j] = tanhf(acc[h][j]);
        }
    }
}

// =====================================================================
// conv3 wave-per-co-pair (512 thr): 8 waves own {w, w+8}; lane owns 1 l.
// =====================================================================
__global__ __launch_bounds__(512) void conv3_wpc(
    const float* __restrict__ in,      // c2 (B,16,1028), valid 1025
    const float* __restrict__ w,       // (16,16,32)
    const float* __restrict__ bias,
    float* __restrict__ out)           // (B,16,260), valid l<257
{
    constexpr int SPAN = 284;
    __shared__ float in_s[16][320];

    int bid = blockIdx.x;
    int tile = bid % 5;
    int b = bid / 5;
    int tid = threadIdx.x;

    int base = tile * 256 - 16;
    const float* inb = in + (size_t)b * 16 * 1028;
    for (int q = tid; q < 16 * (SPAN / 4); q += 512) {
        int ci = q / (SPAN / 4), fp = q - ci * (SPAN / 4);
        int p = 4 * fp;
        float4 v = ld4_guard(inb + (size_t)ci * 1028, base + p, 1025);
        *(float4*)&in_s[ci][pmap(p)] = v;
    }
    __syncthreads();

    int lane = tid & 63;
    int co_u = __builtin_amdgcn_readfirstlane(tid >> 6);   // 0..7

    float acc0 = bias[co_u], acc1 = bias[co_u + 8];

#pragma unroll 1
    for (int ci = 0; ci < 16; ++ci) {
        const float* wa = w + (size_t)(co_u * 16 + ci) * 32;
        const float* wb = w + (size_t)((co_u + 8) * 16 + ci) * 32;
        float4 v[8];
#pragma unroll
        for (int k = 0; k < 8; ++k)
            v[k] = *(const float4*)&in_s[ci][pmap(4 * lane + 4 * k)];
#pragma unroll
        for (int k4 = 0; k4 < 8; ++k4) {
            float4 wva = *(const float4*)(wa + 4 * k4);
            float4 wvb = *(const float4*)(wb + 4 * k4);
            acc0 += v[k4].x * wva.x + v[k4].y * wva.y
                  + v[k4].z * wva.z + v[k4].w * wva.w;
            acc1 += v[k4].x * wvb.x + v[k4].y * wvb.y
                  + v[k4].z * wvb.z + v[k4].w * wvb.w;
        }
    }

    int l3 = tile * 64 + lane;
    if (l3 < 257) {
        out[((size_t)b * 16 + co_u) * 260 + l3] = tanhf(acc0);
        out[((size_t)b * 16 + co_u + 8) * 260 + l3] = tanhf(acc1);
    }
}

// =====================================================================
// conv4 + concat into feats. Block = (b, co-half), pmap-padded st.
// =====================================================================
__global__ __launch_bounds__(256) void conv4_kernel(
    const float* __restrict__ c3,      // (B, 16, 260), valid l3 < 257
    const float* __restrict__ w4, const float* __restrict__ b4,
    float* __restrict__ feats, int ibase)
{
    __shared__ __align__(16) float st[16][320];
    __shared__ float w4s[8][16][32];
    int b = blockIdx.x >> 1, h = blockIdx.x & 1;
    int tid = threadIdx.x;
    for (int i = tid; i < 8 * 16 * 32; i += 256) ((float*)w4s)[i] = w4[h * 4096 + i];
    const float* c3b = c3 + (size_t)b * 16 * 260;
    for (int q = tid; q < 16 * 72; q += 256) {
        int ci = q / 72, p4 = q - ci * 72;
        float4 v = ld4_guard(c3b + (size_t)ci * 260, 4 * p4 - 16, 257);
        *(float4*)&st[ci][pmap(4 * p4)] = v;
    }
    __syncthreads();
    for (int q = tid; q < 520; q += 256) {
        int co_l = q / 65, l4 = q - co_l * 65;
        int co = h * 8 + co_l;
        float acc = b4[co];
#pragma unroll 1
        for (int ci = 0; ci < 16; ++ci) {
#pragma unroll
            for (int k4 = 0; k4 < 8; ++k4) {
                float4 v = *(const float4*)&st[ci][pmap(4 * l4 + 4 * k4)];
                const float* wk = &w4s[co_l][ci][4 * k4];
                acc += v.x * wk[0] + v.y * wk[1] + v.z * wk[2] + v.w * wk[3];
            }
        }
        feats[(size_t)(b & 31) * 2080 + (size_t)((b >> 5) + ibase) * 1040 + co * 65 + l4]
            = tanhf(acc);
    }
}

// =====================================================================
// fc1: (32,2080) @ (128,2080)^T + b -> tanh. Wave per output, float4 dots.
// =====================================================================
__global__ __launch_bounds__(256) void fc1_kernel(const float* __restrict__ h,
                                                  const float* __restrict__ w,
                                                  const float* __restrict__ bias,
                                                  float* __restrict__ out)
{
    int lane = threadIdx.x & 63;
    int wid = blockIdx.x * 4 + (threadIdx.x >> 6);
#pragma unroll
    for (int r = 0; r < 4; ++r) {
        int o = wid + r * 1024;
        int b = o >> 7, j = o & 127;
        const float4* h4 = (const float4*)(h + (size_t)b * 2080);
        const float4* w4 = (const float4*)(w + (size_t)j * 2080);
        float acc = 0.f;
#pragma unroll
        for (int q = 0; q < 8; ++q) {
            float4 a = h4[lane + 64 * q], c = w4[lane + 64 * q];
            acc += a.x * c.x + a.y * c.y + a.z * c.z + a.w * c.w;
        }
        if (lane < 8) {
            float4 a = h4[512 + lane], c = w4[512 + lane];
            acc += a.x * c.x + a.y * c.y + a.z * c.z + a.w * c.w;
        }
        for (int off = 32; off; off >>= 1) acc += __shfl_down(acc, off, 64);
        if (lane == 0) out[b * 128 + j] = tanhf(acc + bias[j]);
    }
}

// =====================================================================
// fc2: (32,128) @ (16,128)^T + b -> tanh. One wave per output.
// =====================================================================
__global__ __launch_bounds__(256) void fc2_kernel(const float* __restrict__ h,
                                                  const float* __restrict__ w,
                                                  const float* __restrict__ bias,
                                                  float* __restrict__ out)
{
    int lane = threadIdx.x & 63;
    int o = blockIdx.x * 4 + (threadIdx.x >> 6);
    int b = o >> 4, j = o & 15;
    const float* hb = h + (size_t)b * 128;
    const float* wj = w + (size_t)j * 128;
    float acc = hb[lane] * wj[lane] + hb[lane + 64] * wj[lane + 64];
    for (int off = 32; off; off >>= 1) acc += __shfl_down(acc, off, 64);
    if (lane == 0) out[o] = tanhf(acc + bias[j]);
}

extern "C" void kernel_launch(void* const* d_in, const int* in_sizes, int n_in,
                              void* d_out, int out_size, void* d_ws, size_t ws_size,
                              hipStream_t stream)
{
    const float* x = (const float*)d_in[0];
    const int* orderings = (const int*)d_in[1];
    const float* sp_w = (const float*)d_in[2];
    const float* sp_b = (const float*)d_in[3];
    const float* conv_w[5];
    const float* conv_b[5];
    for (int j = 0; j < 5; ++j) {
        conv_w[j] = (const float*)d_in[4 + 2 * j];
        conv_b[j] = (const float*)d_in[5 + 2 * j];
    }
    const float* fc1_w = (const float*)d_in[14];
    const float* fc1_b = (const float*)d_in[15];
    const float* fc2_w = (const float*)d_in[16];
    const float* fc2_b = (const float*)d_in[17];

    float* ws = (float*)d_ws;

    if (ws_size >= 12583936ull * 4ull) {
        // ---------- big path: merged B=64, 50.34 MB ----------
        // c0 [0, 4,195,328) over dead xt ; s [4,195,328, 12,583,936) ;
        // c1 [4,195,328, 6,294,528) over dead s ; c2 [6,294,528, 7,347,200) ;
        // c3 [7,347,200, 7,613,440) ; f [7,613,440, 7,680,000) ; h1 after.
        size_t o_xt = 0, o_c0 = 0, o_s = 4195328;
        size_t o_c1 = 4195328, o_c2 = 6294528, o_c3 = 7347200;
        size_t o_f = 7613440, o_h1 = 7680000;

        transpose_kernel<<<NPTS / 64, 256, 0, stream>>>(x, ws + o_xt);
        smooth_kernel<<<512, 256, 0, stream>>>(ws + o_xt, orderings, sp_w, sp_b, ws + o_s);
        smooth_kernel<<<512, 256, 0, stream>>>(ws + o_xt, orderings + NPTS, sp_w, sp_b,
                                               ws + o_s + 4194304);

        conv0_wpc<<<64 * 33, 256, 0, stream>>>(ws + o_s, conv_w[0], conv_b[0], ws + o_c0);
        conv1_wpc<<<64 * 17, 512, 0, stream>>>(ws + o_c0, conv_w[1], conv_b[1], ws + o_c1);
        conv2_wpc<<<64 * 9, 512, 0, stream>>>(ws + o_c1, conv_w[2], conv_b[2], ws + o_c2);
        conv3_wpc<<<64 * 5, 512, 0, stream>>>(ws + o_c2, conv_w[3], conv_b[3], ws + o_c3);
        conv4_kernel<<<128, 256, 0, stream>>>(ws + o_c3, conv_w[4], conv_b[4],
                                              ws + o_f, 0);
        fc1_kernel<<<256, 256, 0, stream>>>(ws + o_f, fc1_w, fc1_b, ws + o_h1);
        fc2_kernel<<<128, 256, 0, stream>>>(ws + o_h1, fc2_w, fc2_b, (float*)d_out);
    } else {
        // ---------- small path: per-SFC, 42.2 MB ----------
        // xt [0,4.19M) ; s [4.19M, 8.39M) ; c0 [8.39M, 10,486,272) ;
        // c1 [4,194,304, 5,243,904) over dead s ; c2 [5,243,904, 5,770,240) ;
        // c3 [5,770,240, 5,903,360) ; f [10,486,272, 10,552,832) ; h1 after.
        size_t o_xt = 0, o_s = 4194304, o_c0 = 8388608;
        size_t o_c1 = 4194304, o_c2 = 5243904, o_c3 = 5770240;
        size_t o_f = 10486272, o_h1 = 10552832;

        transpose_kernel<<<NPTS / 64, 256, 0, stream>>>(x, ws + o_xt);
        for (int i = 0; i < 2; ++i) {
            smooth_kernel<<<512, 256, 0, stream>>>(ws + o_xt, orderings + (size_t)i * NPTS,
                                                   sp_w, sp_b, ws + o_s);
            conv0_wpc<<<32 * 33, 256, 0, stream>>>(ws + o_s, conv_w[0], conv_b[0], ws + o_c0);
            conv1_wpc<<<32 * 17, 512, 0, stream>>>(ws + o_c0, conv_w[1], conv_b[1], ws + o_c1);
            conv2_wpc<<<32 * 9, 512, 0, stream>>>(ws + o_c1, conv_w[2], conv_b[2], ws + o_c2);
            conv3_wpc<<<32 * 5, 512, 0, stream>>>(ws + o_c2, conv_w[3], conv_b[3], ws + o_c3);
            conv4_kernel<<<64, 256, 0, stream>>>(ws + o_c3, conv_w[4], conv_b[4],
                                                 ws + o_f, i);
        }
        fc1_kernel<<<256, 256, 0, stream>>>(ws + o_f, fc1_w, fc1_b, ws + o_h1);
        fc2_kernel<<<128, 256, 0, stream>>>(ws + o_h1, fc2_w, fc2_b, (float*)d_out);
    }
}